// Round 3
// baseline (2191.408 us; speedup 1.0000x reference)
//
#include <hip/hip_runtime.h>
#include <hip/hip_fp16.h>

#define N_NODES 100000
#define N_EDGES 1600000
#define CH 64
#define NLAYERS 3
#define NBUCKC 98          // coarse buckets of 1024 dst nodes
#define SLABC 18432        // coarse slab capacity (mean 16327, sd 127 -> +16 sigma)
#define NFINE (NBUCKC*8)   // 784 fine buckets of 128 dst nodes
#define SLABF 2560         // fine slab capacity (mean 2048, sd 45 -> +11 sigma)
#define EPB 4096           // edges per part1 block (391 blocks)
#define FROW 65            // float stride per node row: odd word stride -> bank spread for atomics

typedef _Float16 half8 __attribute__((ext_vector_type(8)));
typedef float floatx4 __attribute__((ext_vector_type(4)));

static __device__ __forceinline__ float4 ld4(const float* p){ return *(const float4*)p; }
static __device__ __forceinline__ unsigned pack2(float a, float b){
  __half2 h = __float22half2_rn(make_float2(a, b));
  return *(unsigned*)&h;
}
static __device__ __forceinline__ half8 ldh8(const unsigned short* p){
  uint4 u = *(const uint4*)p;
  return *(half8*)&u;
}

// ---- part1: single-pass partition into 98 coarse slabs; packed = src | ((dst&1023)<<20) ----
__global__ __launch_bounds__(256) void part1_kernel(const int* __restrict__ src, const int* __restrict__ dst,
                                                    int* __restrict__ btail, int* __restrict__ pairs){
  __shared__ int lpos[NBUCKC];
  __shared__ int gb[NBUCKC];
  int tid = threadIdx.x;
  if (tid < NBUCKC) lpos[tid] = 0;
  __syncthreads();
  int base = blockIdx.x * EPB;
  int es[EPB/256], ed[EPB/256], er[EPB/256];
  #pragma unroll
  for (int k = 0; k < EPB/256; ++k) {
    int e = base + k*256 + tid;
    if (e < N_EDGES) {
      es[k] = src[e];
      ed[k] = dst[e];
      er[k] = atomicAdd(&lpos[ed[k] >> 10], 1);
    }
  }
  __syncthreads();
  if (tid < NBUCKC) {
    int cc = lpos[tid];
    gb[tid] = cc ? atomicAdd(&btail[tid], cc) : 0;
  }
  __syncthreads();
  #pragma unroll
  for (int k = 0; k < EPB/256; ++k) {
    int e = base + k*256 + tid;
    if (e < N_EDGES) {
      int bk = ed[k] >> 10;
      int idx = gb[bk] + er[k];
      if (idx < (bk+1)*SLABC)                   // memory-safety clamp (statistically never)
        pairs[idx] = es[k] | ((ed[k] & 1023) << 20);
    }
  }
}

// ---- part2: split each coarse slab into 8 fine sub-slabs (784 blocks, 1/8 edge-segment each) ----
__global__ __launch_bounds__(256) void part2_kernel(const int* __restrict__ pairs, const int* __restrict__ btail,
                                                    int* __restrict__ ftail, int* __restrict__ pairs2){
  __shared__ int cnt[8*32];
  __shared__ int scur[8];
  int tid = threadIdx.x;
  int b = blockIdx.x >> 3;
  int sg = blockIdx.x & 7;
  int e0 = b*SLABC;
  int e1 = btail[b]; int emax = e0 + SLABC; if (e1 > emax) e1 = emax;
  int len = e1 - e0;
  int s0 = e0 + (int)(((long)len * sg) >> 3);
  int s1 = e0 + (int)(((long)len * (sg+1)) >> 3);
  cnt[tid] = 0;
  __syncthreads();
  for (int i = s0 + tid; i < s1; i += 256) {
    int p = pairs[i];
    int fk = ((unsigned)p >> 27);
    atomicAdd(&cnt[(fk<<5) + (tid & 31)], 1);
  }
  __syncthreads();
  if (tid < 8) {
    int tot = 0;
    #pragma unroll
    for (int r = 0; r < 32; ++r) tot += cnt[(tid<<5) + r];
    scur[tid] = tot ? atomicAdd(&ftail[(b<<3) + tid], tot) : 0;
  }
  __syncthreads();
  int lane = tid & 63;
  for (int i = s0 + (tid >> 6)*64; i < s1; i += 256) {
    int my = i + lane;
    bool valid = (my < s1);
    int p = valid ? pairs[my] : 0;
    int fk = valid ? (int)((unsigned)p >> 27) : -1;
    #pragma unroll
    for (int j = 0; j < 8; ++j) {
      unsigned long long mask = __ballot(valid && fk == j);
      if (mask) {
        int leader = __ffsll((long long)mask) - 1;
        int cc = __popcll(mask);
        int basep = 0;
        if (lane == leader) basep = atomicAdd(&scur[j], cc);
        basep = __shfl(basep, leader, 64);
        if (valid && fk == j) {
          int rank = __popcll(mask & ((1ull << lane) - 1ull));
          int pos = basep + rank;
          if (pos < ((b<<3) + j + 1)*SLABF)     // memory-safety clamp
            pairs2[pos] = p;
        }
      }
    }
  }
}

// ---- setup: slab cursor init + fold BN into weights (fp16, transposed, XOR-swizzled) ----
__global__ __launch_bounds__(256) void prep_kernel(
    const float* __restrict__ W1, const float* __restrict__ b1,
    const float* __restrict__ g1, const float* __restrict__ be1,
    const float* __restrict__ W2, const float* __restrict__ b2,
    const float* __restrict__ g2, const float* __restrict__ be2,
    const float* __restrict__ bng, const float* __restrict__ bnb,
    _Float16* __restrict__ Wt, float* __restrict__ bf, float* __restrict__ ogb,
    int* __restrict__ btail, int* __restrict__ ftail){
  const float s = 0.9999950000374997f;   // 1/sqrt(1+1e-5)
  int i = blockIdx.x*256 + threadIdx.x;
  if (i < NBUCKC) btail[i] = i*SLABC;
  if (i < NFINE)  ftail[i] = i*SLABF;
  if (i < NLAYERS*4096) {
    int l = i >> 12, rem = i & 4095, k = rem >> 6, n = rem & 63;
    int di = n*64 + (((k>>3) ^ (n&7))<<3) + (k&7);
    Wt[l*8192 + di]        = (_Float16)(W1[i] * g1[l*64+n] * s);
    Wt[l*8192 + 4096 + di] = (_Float16)(W2[i] * g2[l*64+n] * s);
  }
  if (i < NLAYERS*64) {
    int l = i >> 6, j = i & 63;
    bf[l*128 + j]      = b1[i]*g1[i]*s + be1[i];
    bf[l*128 + 64 + j] = b2[i]*g2[i]*s + be2[i];
    ogb[i]                 = bng[i]*s;
    ogb[NLAYERS*64 + i]    = bnb[i];
  }
}

// ---- x0 (fp32) -> XB0 (fp16) ----
__global__ __launch_bounds__(256) void xcvt_kernel(const float* __restrict__ x, unsigned short* __restrict__ xb){
  int i = (blockIdx.x*256 + threadIdx.x)*8;
  if (i < N_NODES*CH) {
    float4 v0 = ld4(x + i), v1 = ld4(x + i + 4);
    uint4 w;
    w.x = pack2(v0.x, v0.y); w.y = pack2(v0.z, v0.w);
    w.z = pack2(v1.x, v1.y); w.w = pack2(v1.z, v1.w);
    *(uint4*)(xb + i) = w;
  }
}

// ---- fused layer: edge-parallel gather + fp32 LDS ds_add_f32 accumulate -> MFMA MLP ----
// One block per fine bucket (128 dst nodes). 8 lanes per edge; uniform work, no degree divergence.
// fp32 LDS accumulation: strictly more precise than baseline's fp16 register chains, and
// native atomicAdd(float*) keeps the DS ops compiler-visible (correct waitcnt before barriers).
__global__ __launch_bounds__(256, 4) void layer_kernel(const unsigned short* __restrict__ XBin,
                                                    const int* __restrict__ pairs2,
                                                    const int* __restrict__ ftail,
                                                    const float* __restrict__ eps,
                                                    const _Float16* __restrict__ Wt,
                                                    const float* __restrict__ bf, const float* __restrict__ ogb,
                                                    int layer, float* __restrict__ outf,
                                                    _Float16* __restrict__ outb, int relu_out){
  __shared__ __align__(16) float Sacc[128*FROW];   // 33.3 KB fp32 acc; reused as fp16 H-tile in MLP phase
  int tid = threadIdx.x;
  int f = blockIdx.x;
  int nodebase = (f>>3)*1024 + (f&7)*128;
  float ep = 1.0f + eps[layer];

  // phase 0: init Sacc with (1+eps)*x_self (fp32, no rounding)
  #pragma unroll
  for (int it = 0; it < 4; ++it) {
    int idx = it*256 + tid;            // (node 0..127) x (kb 0..7)
    int n = idx >> 3, kb0 = idx & 7;
    int gn = nodebase + n;
    float* base = &Sacc[n*FROW + (kb0<<3)];
    if (gn < N_NODES) {
      half8 u = ldh8(XBin + (gn<<6) + (kb0<<3));
      #pragma unroll
      for (int m = 0; m < 8; ++m) base[m] = ep * (float)u[m];
    } else {
      #pragma unroll
      for (int m = 0; m < 8; ++m) base[m] = 0.f;
    }
  }
  __syncthreads();

  // phase 1: edge-parallel gather + fp32 LDS atomic accumulate.
  // atomic bank = (dl + 8*kb + m) mod 32: random dl rotation across the wave's 8 edges -> ~2-way (free).
  int e0 = f*SLABF;
  int e1 = ftail[f]; int emax = e0 + SLABF; if (e1 > emax) e1 = emax;
  int g = tid >> 3, kb = tid & 7;
  #pragma unroll 4
  for (int e = e0 + g; e < e1; e += 32) {
    int p = pairs2[e];
    int srcn = p & 0xFFFFF;
    int dl = ((unsigned)p >> 20) & 127;
    half8 u = ldh8(XBin + (srcn<<6) + (kb<<3));
    float* base = &Sacc[dl*FROW + (kb<<3)];
    #pragma unroll
    for (int m = 0; m < 8; ++m) atomicAdd(&base[m], (float)u[m]);
  }
  __syncthreads();

  // phase 2: MLP. 4 waves x 32 rows each (2 row-tiles). W fragments straight from global (L1-resident).
  int lane = tid & 63;
  int wid = tid >> 6;
  int c = lane & 15;
  int q = lane >> 4;
  int wbase = wid << 5;

  half8 a0[2], a1[2];
  #pragma unroll
  for (int mt = 0; mt < 2; ++mt) {
    int ma = wbase + mt*16 + c;
    const float* pr = &Sacc[ma*FROW];
    half8 x0v, x1v;
    #pragma unroll
    for (int m = 0; m < 8; ++m) x0v[m] = (_Float16)pr[(q<<3) + m];
    #pragma unroll
    for (int m = 0; m < 8; ++m) x1v[m] = (_Float16)pr[32 + (q<<3) + m];
    a0[mt] = x0v; a1[mt] = x1v;
  }

  const _Float16* Wg = Wt + layer*8192;
  floatx4 acc[2][4];
  #pragma unroll
  for (int nt = 0; nt < 4; ++nt) {
    int n = nt*16 + c;
    float bv = bf[layer*128 + n];
    half8 b0 = ldh8((const unsigned short*)(Wg + n*64 + (( q      ^ (n&7))<<3)));
    half8 b1 = ldh8((const unsigned short*)(Wg + n*64 + (((4+q)   ^ (n&7))<<3)));
    #pragma unroll
    for (int mt = 0; mt < 2; ++mt) {
      floatx4 A = {bv, bv, bv, bv};
      A = __builtin_amdgcn_mfma_f32_16x16x32_f16(a0[mt], b0, A, 0, 0, 0);
      A = __builtin_amdgcn_mfma_f32_16x16x32_f16(a1[mt], b1, A, 0, 0, 0);
      acc[mt][nt] = A;
    }
  }
  __syncthreads();                       // all Sacc reads done -> reuse as fp16 H

  _Float16* Hs = (_Float16*)Sacc;
  #pragma unroll
  for (int mt = 0; mt < 2; ++mt)
    #pragma unroll
    for (int nt = 0; nt < 4; ++nt) {
      int n = nt*16 + c;
      #pragma unroll
      for (int r = 0; r < 4; ++r) {
        int m = wbase + mt*16 + (q<<2) + r;
        float h = acc[mt][nt][r]; h = h > 0.f ? h : 0.f;
        Hs[m*64 + (((n>>3) ^ (m&7))<<3) + (n&7)] = (_Float16)h;
      }
    }
  __syncthreads();

  half8 c0[2], c1[2];
  #pragma unroll
  for (int mt = 0; mt < 2; ++mt) {
    int ma = wbase + mt*16 + c;
    c0[mt] = *(const half8*)&Hs[ma*64 + (( q      ^ (ma&7))<<3)];
    c1[mt] = *(const half8*)&Hs[ma*64 + (((4+q)   ^ (ma&7))<<3)];
  }
  floatx4 acc2[2][4];
  #pragma unroll
  for (int nt = 0; nt < 4; ++nt) {
    int n = nt*16 + c;
    float bv = bf[layer*128 + 64 + n];
    half8 b0 = ldh8((const unsigned short*)(Wg + 4096 + n*64 + (( q      ^ (n&7))<<3)));
    half8 b1 = ldh8((const unsigned short*)(Wg + 4096 + n*64 + (((4+q)   ^ (n&7))<<3)));
    #pragma unroll
    for (int mt = 0; mt < 2; ++mt) {
      floatx4 A = {bv, bv, bv, bv};
      A = __builtin_amdgcn_mfma_f32_16x16x32_f16(c0[mt], b0, A, 0, 0, 0);
      A = __builtin_amdgcn_mfma_f32_16x16x32_f16(c1[mt], b1, A, 0, 0, 0);
      acc2[mt][nt] = A;
    }
  }

  #pragma unroll
  for (int nt = 0; nt < 4; ++nt) {
    int n = nt*16 + c;
    float og = ogb[layer*64 + n];
    float ob = ogb[NLAYERS*64 + layer*64 + n];
    #pragma unroll
    for (int mt = 0; mt < 2; ++mt)
      #pragma unroll
      for (int r = 0; r < 4; ++r) {
        int m = wbase + mt*16 + (q<<2) + r;
        int gnode = nodebase + m;
        if (gnode < N_NODES) {
          float h = acc2[mt][nt][r]; h = h > 0.f ? h : 0.f;
          float o = fmaf(og, h, ob);
          if (relu_out) {
            o = o > 0.f ? o : 0.f;
            outb[(size_t)gnode*CH + n] = (_Float16)o;
          } else {
            outf[(size_t)gnode*CH + n] = o;
          }
        }
      }
  }
}

extern "C" void kernel_launch(void* const* d_in, const int* in_sizes, int n_in,
                              void* d_out, int out_size, void* d_ws, size_t ws_size,
                              hipStream_t stream) {
  const float* x0  = (const float*)d_in[0];
  const int*   ei  = (const int*)d_in[1];
  const float* eps = (const float*)d_in[2];
  const float* W1  = (const float*)d_in[3];
  const float* b1  = (const float*)d_in[4];
  const float* g1  = (const float*)d_in[5];
  const float* be1 = (const float*)d_in[6];
  const float* W2  = (const float*)d_in[7];
  const float* b2  = (const float*)d_in[8];
  const float* g2  = (const float*)d_in[9];
  const float* be2 = (const float*)d_in[10];
  const float* bng = (const float*)d_in[11];
  const float* bnb = (const float*)d_in[12];
  const int* src = ei;
  const int* dst = ei + N_EDGES;
  float* OUT = (float*)d_out;

  char* p = (char*)d_ws;
  auto carve = [&](size_t bytes)->char*{ char* r = p; p += (bytes + 255) & ~(size_t)255; return r; };
  int*   btail   = (int*)carve(NBUCKC*sizeof(int));
  int*   ftail   = (int*)carve(NFINE*sizeof(int));
  int*   pairs   = (int*)carve((size_t)NBUCKC*SLABC*sizeof(int));        // 7.2 MB
  int*   pairs2  = (int*)carve((size_t)NFINE*SLABF*sizeof(int));         // 8.0 MB
  unsigned short* XB0 = (unsigned short*)carve((size_t)N_NODES*CH*2);    // 12.8 MB fp16
  unsigned short* XB1 = (unsigned short*)carve((size_t)N_NODES*CH*2);    // 12.8 MB fp16
  _Float16* Wt   = (_Float16*)carve((size_t)NLAYERS*2*4096*2);
  float* bfb     = (float*)carve((size_t)NLAYERS*2*64*sizeof(float));
  float* ogb     = (float*)carve((size_t)2*NLAYERS*64*sizeof(float));

  const int npart = (N_EDGES + EPB - 1)/EPB;   // 391
  prep_kernel<<<48, 256, 0, stream>>>(W1,b1,g1,be1,W2,b2,g2,be2,bng,bnb,Wt,bfb,ogb,btail,ftail);
  part1_kernel<<<npart, 256, 0, stream>>>(src, dst, btail, pairs);
  part2_kernel<<<NFINE, 256, 0, stream>>>(pairs, btail, ftail, pairs2);
  xcvt_kernel<<<(N_NODES*CH/8 + 255)/256, 256, 0, stream>>>(x0, XB0);

  layer_kernel<<<NFINE, 256, 0, stream>>>(XB0, pairs2, ftail, eps, Wt, bfb, ogb, 0, OUT, (_Float16*)XB1, 1);
  layer_kernel<<<NFINE, 256, 0, stream>>>(XB1, pairs2, ftail, eps, Wt, bfb, ogb, 1, OUT, (_Float16*)XB0, 1);
  layer_kernel<<<NFINE, 256, 0, stream>>>(XB0, pairs2, ftail, eps, Wt, bfb, ogb, 2, OUT, (_Float16*)XB1, 0);
}

// Round 4
// 2190.474 us; speedup vs baseline: 1.0004x; 1.0004x over previous
//
#include <hip/hip_runtime.h>
#include <hip/hip_fp16.h>

#define N_NODES 100000
#define N_EDGES 1600000
#define CH 64
#define NLAYERS 3
#define NBUCKC 98          // coarse buckets of 1024 dst nodes
#define SLABC 18432        // coarse slab capacity (mean 16327, sd 127 -> +16 sigma)
#define NFINE (NBUCKC*8)   // 784 fine buckets of 128 dst nodes
#define SLABF 2560         // fine slab capacity (mean 2048, sd 45 -> +11 sigma)
#define EPB 4096           // edges per part1 block (391 blocks)
#define FROW 65            // float stride per node row: odd word stride -> bank spread for atomics

typedef _Float16 half8 __attribute__((ext_vector_type(8)));
typedef float floatx4 __attribute__((ext_vector_type(4)));

static __device__ __forceinline__ float4 ld4(const float* p){ return *(const float4*)p; }
static __device__ __forceinline__ unsigned pack2(float a, float b){
  __half2 h = __float22half2_rn(make_float2(a, b));
  return *(unsigned*)&h;
}
static __device__ __forceinline__ half8 ldh8(const unsigned short* p){
  uint4 u = *(const uint4*)p;
  return *(half8*)&u;
}
// Native LDS fp32 atomic add. HIP's atomicAdd(float*) compiles to a CAS retry loop
// without -munsafe-fp-atomics (round-3: 689us, VALUBusy 1.2% = lgkm-chain stalls).
// ds_add_f32 is fire-and-forget (no return), no RMW loop. addr = LDS byte offset
// (low 32 bits of a generic __shared__ pointer; aperture is 4GiB-aligned - validated
// in round 2/3 where the same idiom produced correct addressing).
// No "memory" clobber so gather loads pipeline across these; ordering before the
// barrier is enforced explicitly (see drain below).
static __device__ __forceinline__ void ds_addf(unsigned addr, float v, int imm){
  switch (imm) {   // imm must be a literal in the asm; callers pass compile-time constants
    case  0: asm volatile("ds_add_f32 %0, %1"           :: "v"(addr), "v"(v)); break;
    case  4: asm volatile("ds_add_f32 %0, %1 offset:4"  :: "v"(addr), "v"(v)); break;
    case  8: asm volatile("ds_add_f32 %0, %1 offset:8"  :: "v"(addr), "v"(v)); break;
    case 12: asm volatile("ds_add_f32 %0, %1 offset:12" :: "v"(addr), "v"(v)); break;
    case 16: asm volatile("ds_add_f32 %0, %1 offset:16" :: "v"(addr), "v"(v)); break;
    case 20: asm volatile("ds_add_f32 %0, %1 offset:20" :: "v"(addr), "v"(v)); break;
    case 24: asm volatile("ds_add_f32 %0, %1 offset:24" :: "v"(addr), "v"(v)); break;
    case 28: asm volatile("ds_add_f32 %0, %1 offset:28" :: "v"(addr), "v"(v)); break;
  }
}

// ---- part1: single-pass partition into 98 coarse slabs; packed = src | ((dst&1023)<<20) ----
__global__ __launch_bounds__(256) void part1_kernel(const int* __restrict__ src, const int* __restrict__ dst,
                                                    int* __restrict__ btail, int* __restrict__ pairs){
  __shared__ int lpos[NBUCKC];
  __shared__ int gb[NBUCKC];
  int tid = threadIdx.x;
  if (tid < NBUCKC) lpos[tid] = 0;
  __syncthreads();
  int base = blockIdx.x * EPB;
  int es[EPB/256], ed[EPB/256], er[EPB/256];
  #pragma unroll
  for (int k = 0; k < EPB/256; ++k) {
    int e = base + k*256 + tid;
    if (e < N_EDGES) {
      es[k] = src[e];
      ed[k] = dst[e];
      er[k] = atomicAdd(&lpos[ed[k] >> 10], 1);
    }
  }
  __syncthreads();
  if (tid < NBUCKC) {
    int cc = lpos[tid];
    gb[tid] = cc ? atomicAdd(&btail[tid], cc) : 0;
  }
  __syncthreads();
  #pragma unroll
  for (int k = 0; k < EPB/256; ++k) {
    int e = base + k*256 + tid;
    if (e < N_EDGES) {
      int bk = ed[k] >> 10;
      int idx = gb[bk] + er[k];
      if (idx < (bk+1)*SLABC)                   // memory-safety clamp (statistically never)
        pairs[idx] = es[k] | ((ed[k] & 1023) << 20);
    }
  }
}

// ---- part2: split each coarse slab into 8 fine sub-slabs (784 blocks, 1/8 edge-segment each) ----
__global__ __launch_bounds__(256) void part2_kernel(const int* __restrict__ pairs, const int* __restrict__ btail,
                                                    int* __restrict__ ftail, int* __restrict__ pairs2){
  __shared__ int cnt[8*32];
  __shared__ int scur[8];
  int tid = threadIdx.x;
  int b = blockIdx.x >> 3;
  int sg = blockIdx.x & 7;
  int e0 = b*SLABC;
  int e1 = btail[b]; int emax = e0 + SLABC; if (e1 > emax) e1 = emax;
  int len = e1 - e0;
  int s0 = e0 + (int)(((long)len * sg) >> 3);
  int s1 = e0 + (int)(((long)len * (sg+1)) >> 3);
  cnt[tid] = 0;
  __syncthreads();
  for (int i = s0 + tid; i < s1; i += 256) {
    int p = pairs[i];
    int fk = ((unsigned)p >> 27);
    atomicAdd(&cnt[(fk<<5) + (tid & 31)], 1);
  }
  __syncthreads();
  if (tid < 8) {
    int tot = 0;
    #pragma unroll
    for (int r = 0; r < 32; ++r) tot += cnt[(tid<<5) + r];
    scur[tid] = tot ? atomicAdd(&ftail[(b<<3) + tid], tot) : 0;
  }
  __syncthreads();
  int lane = tid & 63;
  for (int i = s0 + (tid >> 6)*64; i < s1; i += 256) {
    int my = i + lane;
    bool valid = (my < s1);
    int p = valid ? pairs[my] : 0;
    int fk = valid ? (int)((unsigned)p >> 27) : -1;
    #pragma unroll
    for (int j = 0; j < 8; ++j) {
      unsigned long long mask = __ballot(valid && fk == j);
      if (mask) {
        int leader = __ffsll((long long)mask) - 1;
        int cc = __popcll(mask);
        int basep = 0;
        if (lane == leader) basep = atomicAdd(&scur[j], cc);
        basep = __shfl(basep, leader, 64);
        if (valid && fk == j) {
          int rank = __popcll(mask & ((1ull << lane) - 1ull));
          int pos = basep + rank;
          if (pos < ((b<<3) + j + 1)*SLABF)     // memory-safety clamp
            pairs2[pos] = p;
        }
      }
    }
  }
}

// ---- setup: slab cursor init + fold BN into weights (fp16, transposed, XOR-swizzled) ----
__global__ __launch_bounds__(256) void prep_kernel(
    const float* __restrict__ W1, const float* __restrict__ b1,
    const float* __restrict__ g1, const float* __restrict__ be1,
    const float* __restrict__ W2, const float* __restrict__ b2,
    const float* __restrict__ g2, const float* __restrict__ be2,
    const float* __restrict__ bng, const float* __restrict__ bnb,
    _Float16* __restrict__ Wt, float* __restrict__ bf, float* __restrict__ ogb,
    int* __restrict__ btail, int* __restrict__ ftail){
  const float s = 0.9999950000374997f;   // 1/sqrt(1+1e-5)
  int i = blockIdx.x*256 + threadIdx.x;
  if (i < NBUCKC) btail[i] = i*SLABC;
  if (i < NFINE)  ftail[i] = i*SLABF;
  if (i < NLAYERS*4096) {
    int l = i >> 12, rem = i & 4095, k = rem >> 6, n = rem & 63;
    int di = n*64 + (((k>>3) ^ (n&7))<<3) + (k&7);
    Wt[l*8192 + di]        = (_Float16)(W1[i] * g1[l*64+n] * s);
    Wt[l*8192 + 4096 + di] = (_Float16)(W2[i] * g2[l*64+n] * s);
  }
  if (i < NLAYERS*64) {
    int l = i >> 6, j = i & 63;
    bf[l*128 + j]      = b1[i]*g1[i]*s + be1[i];
    bf[l*128 + 64 + j] = b2[i]*g2[i]*s + be2[i];
    ogb[i]                 = bng[i]*s;
    ogb[NLAYERS*64 + i]    = bnb[i];
  }
}

// ---- x0 (fp32) -> XB0 (fp16) ----
__global__ __launch_bounds__(256) void xcvt_kernel(const float* __restrict__ x, unsigned short* __restrict__ xb){
  int i = (blockIdx.x*256 + threadIdx.x)*8;
  if (i < N_NODES*CH) {
    float4 v0 = ld4(x + i), v1 = ld4(x + i + 4);
    uint4 w;
    w.x = pack2(v0.x, v0.y); w.y = pack2(v0.z, v0.w);
    w.z = pack2(v1.x, v1.y); w.w = pack2(v1.z, v1.w);
    *(uint4*)(xb + i) = w;
  }
}

// ---- fused layer: edge-parallel gather + fp32 LDS ds_add_f32 accumulate -> MFMA MLP ----
// One block per fine bucket (128 dst nodes). 8 lanes per edge; uniform work, no degree divergence.
__global__ __launch_bounds__(256, 4) void layer_kernel(const unsigned short* __restrict__ XBin,
                                                    const int* __restrict__ pairs2,
                                                    const int* __restrict__ ftail,
                                                    const float* __restrict__ eps,
                                                    const _Float16* __restrict__ Wt,
                                                    const float* __restrict__ bf, const float* __restrict__ ogb,
                                                    int layer, float* __restrict__ outf,
                                                    _Float16* __restrict__ outb, int relu_out){
  __shared__ __align__(16) float Sacc[128*FROW];   // 33.3 KB fp32 acc; reused as fp16 H-tile in MLP phase
  int tid = threadIdx.x;
  int f = blockIdx.x;
  int nodebase = (f>>3)*1024 + (f&7)*128;
  float ep = 1.0f + eps[layer];

  // phase 0: init Sacc with (1+eps)*x_self (fp32, no rounding)
  #pragma unroll
  for (int it = 0; it < 4; ++it) {
    int idx = it*256 + tid;            // (node 0..127) x (kb 0..7)
    int n = idx >> 3, kb0 = idx & 7;
    int gn = nodebase + n;
    float* base = &Sacc[n*FROW + (kb0<<3)];
    if (gn < N_NODES) {
      half8 u = ldh8(XBin + (gn<<6) + (kb0<<3));
      #pragma unroll
      for (int m = 0; m < 8; ++m) base[m] = ep * (float)u[m];
    } else {
      #pragma unroll
      for (int m = 0; m < 8; ++m) base[m] = 0.f;
    }
  }
  __syncthreads();

  // phase 1: edge-parallel gather + native fp32 LDS atomic accumulate (ds_add_f32).
  // atomic bank = (dl + 8*kb + m) mod 32: random dl rotation across the wave's 8 edges -> ~2-way (free).
  int e0 = f*SLABF;
  int e1 = ftail[f]; int emax = e0 + SLABF; if (e1 > emax) e1 = emax;
  int g = tid >> 3, kb = tid & 7;
  #pragma unroll 4
  for (int e = e0 + g; e < e1; e += 32) {
    int p = pairs2[e];
    int srcn = p & 0xFFFFF;
    int dl = ((unsigned)p >> 20) & 127;
    half8 u = ldh8(XBin + (srcn<<6) + (kb<<3));
    unsigned a = (unsigned)(uintptr_t)(&Sacc[dl*FROW + (kb<<3)]);
    #pragma unroll
    for (int m = 0; m < 8; ++m) ds_addf(a, (float)u[m], m*4);
  }
  // Drain the asm DS atomics before the barrier: they are invisible to the compiler's
  // waitcnt insertion (rule 18). sched_barrier pins ordering.
  asm volatile("s_waitcnt lgkmcnt(0)" ::: "memory");
  __builtin_amdgcn_sched_barrier(0);
  __syncthreads();

  // phase 2: MLP. 4 waves x 32 rows each (2 row-tiles). W fragments straight from global (L1-resident).
  int lane = tid & 63;
  int wid = tid >> 6;
  int c = lane & 15;
  int q = lane >> 4;
  int wbase = wid << 5;

  half8 a0[2], a1[2];
  #pragma unroll
  for (int mt = 0; mt < 2; ++mt) {
    int ma = wbase + mt*16 + c;
    const float* pr = &Sacc[ma*FROW];
    half8 x0v, x1v;
    #pragma unroll
    for (int m = 0; m < 8; ++m) x0v[m] = (_Float16)pr[(q<<3) + m];
    #pragma unroll
    for (int m = 0; m < 8; ++m) x1v[m] = (_Float16)pr[32 + (q<<3) + m];
    a0[mt] = x0v; a1[mt] = x1v;
  }

  const _Float16* Wg = Wt + layer*8192;
  floatx4 acc[2][4];
  #pragma unroll
  for (int nt = 0; nt < 4; ++nt) {
    int n = nt*16 + c;
    float bv = bf[layer*128 + n];
    half8 b0 = ldh8((const unsigned short*)(Wg + n*64 + (( q      ^ (n&7))<<3)));
    half8 b1 = ldh8((const unsigned short*)(Wg + n*64 + (((4+q)   ^ (n&7))<<3)));
    #pragma unroll
    for (int mt = 0; mt < 2; ++mt) {
      floatx4 A = {bv, bv, bv, bv};
      A = __builtin_amdgcn_mfma_f32_16x16x32_f16(a0[mt], b0, A, 0, 0, 0);
      A = __builtin_amdgcn_mfma_f32_16x16x32_f16(a1[mt], b1, A, 0, 0, 0);
      acc[mt][nt] = A;
    }
  }
  __syncthreads();                       // all Sacc reads done -> reuse as fp16 H

  _Float16* Hs = (_Float16*)Sacc;
  #pragma unroll
  for (int mt = 0; mt < 2; ++mt)
    #pragma unroll
    for (int nt = 0; nt < 4; ++nt) {
      int n = nt*16 + c;
      #pragma unroll
      for (int r = 0; r < 4; ++r) {
        int m = wbase + mt*16 + (q<<2) + r;
        float h = acc[mt][nt][r]; h = h > 0.f ? h : 0.f;
        Hs[m*64 + (((n>>3) ^ (m&7))<<3) + (n&7)] = (_Float16)h;
      }
    }
  __syncthreads();

  half8 c0[2], c1[2];
  #pragma unroll
  for (int mt = 0; mt < 2; ++mt) {
    int ma = wbase + mt*16 + c;
    c0[mt] = *(const half8*)&Hs[ma*64 + (( q      ^ (ma&7))<<3)];
    c1[mt] = *(const half8*)&Hs[ma*64 + (((4+q)   ^ (ma&7))<<3)];
  }
  floatx4 acc2[2][4];
  #pragma unroll
  for (int nt = 0; nt < 4; ++nt) {
    int n = nt*16 + c;
    float bv = bf[layer*128 + 64 + n];
    half8 b0 = ldh8((const unsigned short*)(Wg + 4096 + n*64 + (( q      ^ (n&7))<<3)));
    half8 b1 = ldh8((const unsigned short*)(Wg + 4096 + n*64 + (((4+q)   ^ (n&7))<<3)));
    #pragma unroll
    for (int mt = 0; mt < 2; ++mt) {
      floatx4 A = {bv, bv, bv, bv};
      A = __builtin_amdgcn_mfma_f32_16x16x32_f16(c0[mt], b0, A, 0, 0, 0);
      A = __builtin_amdgcn_mfma_f32_16x16x32_f16(c1[mt], b1, A, 0, 0, 0);
      acc2[mt][nt] = A;
    }
  }

  #pragma unroll
  for (int nt = 0; nt < 4; ++nt) {
    int n = nt*16 + c;
    float og = ogb[layer*64 + n];
    float ob = ogb[NLAYERS*64 + layer*64 + n];
    #pragma unroll
    for (int mt = 0; mt < 2; ++mt)
      #pragma unroll
      for (int r = 0; r < 4; ++r) {
        int m = wbase + mt*16 + (q<<2) + r;
        int gnode = nodebase + m;
        if (gnode < N_NODES) {
          float h = acc2[mt][nt][r]; h = h > 0.f ? h : 0.f;
          float o = fmaf(og, h, ob);
          if (relu_out) {
            o = o > 0.f ? o : 0.f;
            outb[(size_t)gnode*CH + n] = (_Float16)o;
          } else {
            outf[(size_t)gnode*CH + n] = o;
          }
        }
      }
  }
}

extern "C" void kernel_launch(void* const* d_in, const int* in_sizes, int n_in,
                              void* d_out, int out_size, void* d_ws, size_t ws_size,
                              hipStream_t stream) {
  const float* x0  = (const float*)d_in[0];
  const int*   ei  = (const int*)d_in[1];
  const float* eps = (const float*)d_in[2];
  const float* W1  = (const float*)d_in[3];
  const float* b1  = (const float*)d_in[4];
  const float* g1  = (const float*)d_in[5];
  const float* be1 = (const float*)d_in[6];
  const float* W2  = (const float*)d_in[7];
  const float* b2  = (const float*)d_in[8];
  const float* g2  = (const float*)d_in[9];
  const float* be2 = (const float*)d_in[10];
  const float* bng = (const float*)d_in[11];
  const float* bnb = (const float*)d_in[12];
  const int* src = ei;
  const int* dst = ei + N_EDGES;
  float* OUT = (float*)d_out;

  char* p = (char*)d_ws;
  auto carve = [&](size_t bytes)->char*{ char* r = p; p += (bytes + 255) & ~(size_t)255; return r; };
  int*   btail   = (int*)carve(NBUCKC*sizeof(int));
  int*   ftail   = (int*)carve(NFINE*sizeof(int));
  int*   pairs   = (int*)carve((size_t)NBUCKC*SLABC*sizeof(int));        // 7.2 MB
  int*   pairs2  = (int*)carve((size_t)NFINE*SLABF*sizeof(int));         // 8.0 MB
  unsigned short* XB0 = (unsigned short*)carve((size_t)N_NODES*CH*2);    // 12.8 MB fp16
  unsigned short* XB1 = (unsigned short*)carve((size_t)N_NODES*CH*2);    // 12.8 MB fp16
  _Float16* Wt   = (_Float16*)carve((size_t)NLAYERS*2*4096*2);
  float* bfb     = (float*)carve((size_t)NLAYERS*2*64*sizeof(float));
  float* ogb     = (float*)carve((size_t)2*NLAYERS*64*sizeof(float));

  const int npart = (N_EDGES + EPB - 1)/EPB;   // 391
  prep_kernel<<<48, 256, 0, stream>>>(W1,b1,g1,be1,W2,b2,g2,be2,bng,bnb,Wt,bfb,ogb,btail,ftail);
  part1_kernel<<<npart, 256, 0, stream>>>(src, dst, btail, pairs);
  part2_kernel<<<NFINE, 256, 0, stream>>>(pairs, btail, ftail, pairs2);
  xcvt_kernel<<<(N_NODES*CH/8 + 255)/256, 256, 0, stream>>>(x0, XB0);

  layer_kernel<<<NFINE, 256, 0, stream>>>(XB0, pairs2, ftail, eps, Wt, bfb, ogb, 0, OUT, (_Float16*)XB1, 1);
  layer_kernel<<<NFINE, 256, 0, stream>>>(XB1, pairs2, ftail, eps, Wt, bfb, ogb, 1, OUT, (_Float16*)XB0, 1);
  layer_kernel<<<NFINE, 256, 0, stream>>>(XB0, pairs2, ftail, eps, Wt, bfb, ogb, 2, OUT, (_Float16*)XB1, 0);
}

// Round 5
// 267.676 us; speedup vs baseline: 8.1868x; 8.1833x over previous
//
#include <hip/hip_runtime.h>
#include <hip/hip_fp16.h>

#define N_NODES 100000
#define N_EDGES 1600000
#define CH 64
#define NLAYERS 3
#define NBUCKC 98          // coarse buckets of 1024 dst nodes
#define SLABC 18432        // coarse slab capacity (mean 16327, sd 127 -> +16 sigma)
#define NFINE (NBUCKC*8)   // 784 fine buckets of 128 dst nodes
#define SLABF 2560         // fine slab capacity (mean 2048, sd 45 -> +11 sigma)
#define EPB 4096           // edges per part1 block (391 blocks)

typedef _Float16 half8 __attribute__((ext_vector_type(8)));
typedef float floatx4 __attribute__((ext_vector_type(4)));

static __device__ __forceinline__ float4 ld4(const float* p){ return *(const float4*)p; }
static __device__ __forceinline__ unsigned pack2(float a, float b){
  __half2 h = __float22half2_rn(make_float2(a, b));
  return *(unsigned*)&h;
}
static __device__ __forceinline__ half8 ldh8(const unsigned short* p){
  uint4 u = *(const uint4*)p;
  return *(half8*)&u;
}

// ---- part1: single-pass partition into 98 coarse slabs; packed = src | ((dst&1023)<<20) ----
__global__ __launch_bounds__(256) void part1_kernel(const int* __restrict__ src, const int* __restrict__ dst,
                                                    int* __restrict__ btail, int* __restrict__ pairs){
  __shared__ int lpos[NBUCKC];
  __shared__ int gb[NBUCKC];
  int tid = threadIdx.x;
  if (tid < NBUCKC) lpos[tid] = 0;
  __syncthreads();
  int base = blockIdx.x * EPB;
  int es[EPB/256], ed[EPB/256], er[EPB/256];
  #pragma unroll
  for (int k = 0; k < EPB/256; ++k) {
    int e = base + k*256 + tid;
    if (e < N_EDGES) {
      es[k] = src[e];
      ed[k] = dst[e];
      er[k] = atomicAdd(&lpos[ed[k] >> 10], 1);
    }
  }
  __syncthreads();
  if (tid < NBUCKC) {
    int cc = lpos[tid];
    gb[tid] = cc ? atomicAdd(&btail[tid], cc) : 0;
  }
  __syncthreads();
  #pragma unroll
  for (int k = 0; k < EPB/256; ++k) {
    int e = base + k*256 + tid;
    if (e < N_EDGES) {
      int bk = ed[k] >> 10;
      int idx = gb[bk] + er[k];
      if (idx < (bk+1)*SLABC)                   // memory-safety clamp (statistically never)
        pairs[idx] = es[k] | ((ed[k] & 1023) << 20);
    }
  }
}

// ---- part2: split each coarse slab into 8 fine sub-slabs (784 blocks, 1/8 edge-segment each) ----
__global__ __launch_bounds__(256) void part2_kernel(const int* __restrict__ pairs, const int* __restrict__ btail,
                                                    int* __restrict__ ftail, int* __restrict__ pairs2){
  __shared__ int cnt[8*32];
  __shared__ int scur[8];
  int tid = threadIdx.x;
  int b = blockIdx.x >> 3;
  int sg = blockIdx.x & 7;
  int e0 = b*SLABC;
  int e1 = btail[b]; int emax = e0 + SLABC; if (e1 > emax) e1 = emax;
  int len = e1 - e0;
  int s0 = e0 + (int)(((long)len * sg) >> 3);
  int s1 = e0 + (int)(((long)len * (sg+1)) >> 3);
  cnt[tid] = 0;
  __syncthreads();
  for (int i = s0 + tid; i < s1; i += 256) {
    int p = pairs[i];
    int fk = ((unsigned)p >> 27);
    atomicAdd(&cnt[(fk<<5) + (tid & 31)], 1);
  }
  __syncthreads();
  if (tid < 8) {
    int tot = 0;
    #pragma unroll
    for (int r = 0; r < 32; ++r) tot += cnt[(tid<<5) + r];
    scur[tid] = tot ? atomicAdd(&ftail[(b<<3) + tid], tot) : 0;
  }
  __syncthreads();
  int lane = tid & 63;
  for (int i = s0 + (tid >> 6)*64; i < s1; i += 256) {
    int my = i + lane;
    bool valid = (my < s1);
    int p = valid ? pairs[my] : 0;
    int fk = valid ? (int)((unsigned)p >> 27) : -1;
    #pragma unroll
    for (int j = 0; j < 8; ++j) {
      unsigned long long mask = __ballot(valid && fk == j);
      if (mask) {
        int leader = __ffsll((long long)mask) - 1;
        int cc = __popcll(mask);
        int basep = 0;
        if (lane == leader) basep = atomicAdd(&scur[j], cc);
        basep = __shfl(basep, leader, 64);
        if (valid && fk == j) {
          int rank = __popcll(mask & ((1ull << lane) - 1ull));
          int pos = basep + rank;
          if (pos < ((b<<3) + j + 1)*SLABF)     // memory-safety clamp
            pairs2[pos] = p;
        }
      }
    }
  }
}

// ---- csr: per fine sub-slab (784 blocks): hist 128 nodes, scan, scatter ----
__global__ __launch_bounds__(256) void csr_kernel(const int* __restrict__ pairs2, const int* __restrict__ ftail,
                                                  int* __restrict__ offs, int* __restrict__ offe,
                                                  int* __restrict__ srclist){
  __shared__ int c[128];
  __shared__ int s[128];
  __shared__ int cur[128];
  int t = threadIdx.x;
  int f = blockIdx.x;
  int e0 = f*SLABF;
  int e1 = ftail[f]; int emax = e0 + SLABF; if (e1 > emax) e1 = emax;
  if (t < 128) c[t] = 0;
  __syncthreads();
  for (int i = e0 + t; i < e1; i += 256) {
    int p = pairs2[i];
    atomicAdd(&c[((unsigned)p >> 20) & 127], 1);
  }
  __syncthreads();
  int v = (t < 128) ? c[t] : 0;
  if (t < 128) s[t] = v;
  __syncthreads();
  #pragma unroll
  for (int o = 1; o < 128; o <<= 1){
    int u = 0;
    if (t < 128 && t >= o) u = s[t-o];
    __syncthreads();
    if (t < 128) s[t] += u;
    __syncthreads();
  }
  if (t < 128) {
    int excl = s[t] - v;
    cur[t] = excl;
    int n = (f >> 3)*1024 + (f & 7)*128 + t;
    if (n < N_NODES) { offs[n] = e0 + excl; offe[n] = e0 + excl + v; }
  }
  __syncthreads();
  for (int i = e0 + t; i < e1; i += 256) {
    int p = pairs2[i];
    int pos = atomicAdd(&cur[((unsigned)p >> 20) & 127], 1);
    if (pos < SLABF)                            // memory-safety clamp
      srclist[e0 + pos] = p & 0xFFFFF;
  }
}

// ---- setup: slab cursor init + fold BN into weights (fp16, transposed, XOR-swizzled) ----
__global__ __launch_bounds__(256) void prep_kernel(
    const float* __restrict__ W1, const float* __restrict__ b1,
    const float* __restrict__ g1, const float* __restrict__ be1,
    const float* __restrict__ W2, const float* __restrict__ b2,
    const float* __restrict__ g2, const float* __restrict__ be2,
    const float* __restrict__ bng, const float* __restrict__ bnb,
    _Float16* __restrict__ Wt, float* __restrict__ bf, float* __restrict__ ogb,
    int* __restrict__ btail, int* __restrict__ ftail){
  const float s = 0.9999950000374997f;   // 1/sqrt(1+1e-5)
  int i = blockIdx.x*256 + threadIdx.x;
  if (i < NBUCKC) btail[i] = i*SLABC;
  if (i < NFINE)  ftail[i] = i*SLABF;
  if (i < NLAYERS*4096) {
    int l = i >> 12, rem = i & 4095, k = rem >> 6, n = rem & 63;
    int di = n*64 + (((k>>3) ^ (n&7))<<3) + (k&7);
    Wt[l*8192 + di]        = (_Float16)(W1[i] * g1[l*64+n] * s);
    Wt[l*8192 + 4096 + di] = (_Float16)(W2[i] * g2[l*64+n] * s);
  }
  if (i < NLAYERS*64) {
    int l = i >> 6, j = i & 63;
    bf[l*128 + j]      = b1[i]*g1[i]*s + be1[i];
    bf[l*128 + 64 + j] = b2[i]*g2[i]*s + be2[i];
    ogb[i]                 = bng[i]*s;
    ogb[NLAYERS*64 + i]    = bnb[i];
  }
}

// ---- x0 (fp32) -> XB0 (fp16) ----
__global__ __launch_bounds__(256) void xcvt_kernel(const float* __restrict__ x, unsigned short* __restrict__ xb){
  int i = (blockIdx.x*256 + threadIdx.x)*8;
  if (i < N_NODES*CH) {
    float4 v0 = ld4(x + i), v1 = ld4(x + i + 4);
    uint4 w;
    w.x = pack2(v0.x, v0.y); w.y = pack2(v0.z, v0.w);
    w.z = pack2(v1.x, v1.y); w.w = pack2(v1.z, v1.w);
    *(uint4*)(xb + i) = w;
  }
}

// ---- fused layer: SW-pipelined gather (8 chains, double-buffered batches) -> MFMA MLP ----
// __launch_bounds__(256, 8): 8 waves/EU -> up to 8 blocks/CU (VGPR 44<=64, LDS 16KB*8=128KB<=160KB).
// Round-0 counters showed latency-bound (VALUBusy 20%, occupancy 34%); more resident gather
// chains is the cheapest latency-hiding lever.
__global__ __launch_bounds__(256, 8) void layer_kernel(const unsigned short* __restrict__ XBin,
                                                    const int* __restrict__ offs, const int* __restrict__ offe,
                                                    const int* __restrict__ srclist,
                                                    const float* __restrict__ eps,
                                                    const _Float16* __restrict__ Wt,
                                                    const float* __restrict__ bf, const float* __restrict__ ogb,
                                                    int layer, float* __restrict__ outf,
                                                    _Float16* __restrict__ outb, int relu_out){
  __shared__ _Float16 HsA[64*64];
  __shared__ _Float16 Wts[64*64];
  int tid = threadIdx.x;
  int b = blockIdx.x;
  const _Float16* Wg = Wt + layer*8192;
  *(uint4*)&Wts[tid*8]       = *(const uint4*)&Wg[tid*8];
  *(uint4*)&Wts[(tid+256)*8] = *(const uint4*)&Wg[(tid+256)*8];

  float ep = 1.0f + eps[layer];
  int kb = tid & 7;
  const unsigned short* xr = XBin + (kb << 3);
  #pragma unroll
  for (int p = 0; p < 2; ++p) {
    int nl = p*32 + (tid >> 3);
    int n = b*64 + nl;
    float r[8] = {0,0,0,0,0,0,0,0};
    if (n < N_NODES) {
      half8 A = (half8)(_Float16)0, B = A, C = A, D = A, E = A, F = A, G = A, H = A;
      int e0 = offs[n], e1 = offe[n];
      int e = e0;
      if (e + 8 <= e1) {
        // prologue: batch 0 in flight
        half8 u0 = ldh8(xr + (srclist[e  ]<<6));
        half8 u1 = ldh8(xr + (srclist[e+1]<<6));
        half8 u2 = ldh8(xr + (srclist[e+2]<<6));
        half8 u3 = ldh8(xr + (srclist[e+3]<<6));
        half8 u4 = ldh8(xr + (srclist[e+4]<<6));
        half8 u5 = ldh8(xr + (srclist[e+5]<<6));
        half8 u6 = ldh8(xr + (srclist[e+6]<<6));
        half8 u7 = ldh8(xr + (srclist[e+7]<<6));
        e += 8;
        // steady state: issue batch i+1, then consume batch i
        for (; e + 8 <= e1; e += 8) {
          half8 v0 = ldh8(xr + (srclist[e  ]<<6));
          half8 v1 = ldh8(xr + (srclist[e+1]<<6));
          half8 v2 = ldh8(xr + (srclist[e+2]<<6));
          half8 v3 = ldh8(xr + (srclist[e+3]<<6));
          half8 v4 = ldh8(xr + (srclist[e+4]<<6));
          half8 v5 = ldh8(xr + (srclist[e+5]<<6));
          half8 v6 = ldh8(xr + (srclist[e+6]<<6));
          half8 v7 = ldh8(xr + (srclist[e+7]<<6));
          A += u0; B += u1; C += u2; D += u3;
          E += u4; F += u5; G += u6; H += u7;
          u0 = v0; u1 = v1; u2 = v2; u3 = v3;
          u4 = v4; u5 = v5; u6 = v6; u7 = v7;
        }
        A += u0; B += u1; C += u2; D += u3;
        E += u4; F += u5; G += u6; H += u7;
      }
      for (; e+4 <= e1; e += 4) {
        half8 u0 = ldh8(xr + (srclist[e  ]<<6));
        half8 u1 = ldh8(xr + (srclist[e+1]<<6));
        half8 u2 = ldh8(xr + (srclist[e+2]<<6));
        half8 u3 = ldh8(xr + (srclist[e+3]<<6));
        A += u0; B += u1; C += u2; D += u3;
      }
      for (; e < e1; ++e) {
        A += ldh8(xr + (srclist[e]<<6));
      }
      half8 S = ((A + B) + (C + D)) + ((E + F) + (G + H));
      half8 sv = ldh8(xr + (n<<6));
      #pragma unroll
      for (int i = 0; i < 8; ++i) r[i] = fmaf(ep, (float)sv[i], (float)S[i]);
    }
    uint4 w;
    w.x = pack2(r[0], r[1]); w.y = pack2(r[2], r[3]);
    w.z = pack2(r[4], r[5]); w.w = pack2(r[6], r[7]);
    *(uint4*)&HsA[nl*64 + ((kb ^ (nl&7))<<3)] = w;
  }
  __syncthreads();

  int lane = tid & 63;
  int wid = tid >> 6;
  int c = lane & 15;
  int q = lane >> 4;
  int mbase = wid*16;
  int ma = mbase + c;

  half8 a0 = *(const half8*)&HsA[ma*64 + (((q)   ^ (ma&7))<<3)];
  half8 a1 = *(const half8*)&HsA[ma*64 + (((4+q) ^ (ma&7))<<3)];

  floatx4 acc[4];
  #pragma unroll
  for (int nt = 0; nt < 4; ++nt) {
    int n = nt*16 + c;
    float bv = bf[layer*128 + n];
    floatx4 Acc = {bv, bv, bv, bv};
    half8 b0 = *(const half8*)&Wts[n*64 + (((q)   ^ (n&7))<<3)];
    half8 b1 = *(const half8*)&Wts[n*64 + (((4+q) ^ (n&7))<<3)];
    Acc = __builtin_amdgcn_mfma_f32_16x16x32_f16(a0, b0, Acc, 0, 0, 0);
    Acc = __builtin_amdgcn_mfma_f32_16x16x32_f16(a1, b1, Acc, 0, 0, 0);
    acc[nt] = Acc;
  }
  __syncthreads();

  #pragma unroll
  for (int nt = 0; nt < 4; ++nt) {
    int n = nt*16 + c;
    #pragma unroll
    for (int r = 0; r < 4; ++r) {
      int m = mbase + q*4 + r;
      float h = acc[nt][r]; h = h > 0.f ? h : 0.f;
      HsA[m*64 + (((n>>3) ^ (m&7))<<3) + (n&7)] = (_Float16)h;
    }
  }
  *(uint4*)&Wts[tid*8]       = *(const uint4*)&Wg[4096 + tid*8];
  *(uint4*)&Wts[(tid+256)*8] = *(const uint4*)&Wg[4096 + (tid+256)*8];
  __syncthreads();

  half8 c0 = *(const half8*)&HsA[ma*64 + (((q)   ^ (ma&7))<<3)];
  half8 c1 = *(const half8*)&HsA[ma*64 + (((4+q) ^ (ma&7))<<3)];
  floatx4 acc2[4];
  #pragma unroll
  for (int nt = 0; nt < 4; ++nt) {
    int n = nt*16 + c;
    float bv = bf[layer*128 + 64 + n];
    floatx4 Acc = {bv, bv, bv, bv};
    half8 b0 = *(const half8*)&Wts[n*64 + (((q)   ^ (n&7))<<3)];
    half8 b1 = *(const half8*)&Wts[n*64 + (((4+q) ^ (n&7))<<3)];
    Acc = __builtin_amdgcn_mfma_f32_16x16x32_f16(c0, b0, Acc, 0, 0, 0);
    Acc = __builtin_amdgcn_mfma_f32_16x16x32_f16(c1, b1, Acc, 0, 0, 0);
    acc2[nt] = Acc;
  }

  #pragma unroll
  for (int nt = 0; nt < 4; ++nt) {
    int n = nt*16 + c;
    float og = ogb[layer*64 + n];
    float ob = ogb[NLAYERS*64 + layer*64 + n];
    #pragma unroll
    for (int r = 0; r < 4; ++r) {
      int m = mbase + q*4 + r;
      int gnode = b*64 + m;
      if (gnode < N_NODES) {
        float h = acc2[nt][r]; h = h > 0.f ? h : 0.f;
        float o = fmaf(og, h, ob);
        if (relu_out) {
          o = o > 0.f ? o : 0.f;
          outb[(size_t)gnode*CH + n] = (_Float16)o;
        } else {
          outf[(size_t)gnode*CH + n] = o;
        }
      }
    }
  }
}

extern "C" void kernel_launch(void* const* d_in, const int* in_sizes, int n_in,
                              void* d_out, int out_size, void* d_ws, size_t ws_size,
                              hipStream_t stream) {
  const float* x0  = (const float*)d_in[0];
  const int*   ei  = (const int*)d_in[1];
  const float* eps = (const float*)d_in[2];
  const float* W1  = (const float*)d_in[3];
  const float* b1  = (const float*)d_in[4];
  const float* g1  = (const float*)d_in[5];
  const float* be1 = (const float*)d_in[6];
  const float* W2  = (const float*)d_in[7];
  const float* b2  = (const float*)d_in[8];
  const float* g2  = (const float*)d_in[9];
  const float* be2 = (const float*)d_in[10];
  const float* bng = (const float*)d_in[11];
  const float* bnb = (const float*)d_in[12];
  const int* src = ei;
  const int* dst = ei + N_EDGES;
  float* OUT = (float*)d_out;

  char* p = (char*)d_ws;
  auto carve = [&](size_t bytes)->char*{ char* r = p; p += (bytes + 255) & ~(size_t)255; return r; };
  int*   offs    = (int*)carve((size_t)N_NODES*sizeof(int));
  int*   offe    = (int*)carve((size_t)N_NODES*sizeof(int));
  int*   btail   = (int*)carve(NBUCKC*sizeof(int));
  int*   ftail   = (int*)carve(NFINE*sizeof(int));
  int*   pairs   = (int*)carve((size_t)NBUCKC*SLABC*sizeof(int));        // 7.2 MB
  int*   pairs2  = (int*)carve((size_t)NFINE*SLABF*sizeof(int));         // 8.0 MB
  int*   srclist = (int*)carve((size_t)NFINE*SLABF*sizeof(int));         // 8.0 MB
  unsigned short* XB0 = (unsigned short*)carve((size_t)N_NODES*CH*2);    // 12.8 MB fp16
  unsigned short* XB1 = (unsigned short*)carve((size_t)N_NODES*CH*2);    // 12.8 MB fp16
  _Float16* Wt   = (_Float16*)carve((size_t)NLAYERS*2*4096*2);
  float* bfb     = (float*)carve((size_t)NLAYERS*2*64*sizeof(float));
  float* ogb     = (float*)carve((size_t)2*NLAYERS*64*sizeof(float));

  const int npart = (N_EDGES + EPB - 1)/EPB;   // 391
  prep_kernel<<<48, 256, 0, stream>>>(W1,b1,g1,be1,W2,b2,g2,be2,bng,bnb,Wt,bfb,ogb,btail,ftail);
  part1_kernel<<<npart, 256, 0, stream>>>(src, dst, btail, pairs);
  part2_kernel<<<NFINE, 256, 0, stream>>>(pairs, btail, ftail, pairs2);
  csr_kernel<<<NFINE, 256, 0, stream>>>(pairs2, ftail, offs, offe, srclist);
  xcvt_kernel<<<(N_NODES*CH/8 + 255)/256, 256, 0, stream>>>(x0, XB0);

  const int nlb = (N_NODES + 63)/64;   // 1563
  layer_kernel<<<nlb, 256, 0, stream>>>(XB0, offs, offe, srclist, eps, Wt, bfb, ogb, 0, OUT, (_Float16*)XB1, 1);
  layer_kernel<<<nlb, 256, 0, stream>>>(XB1, offs, offe, srclist, eps, Wt, bfb, ogb, 1, OUT, (_Float16*)XB0, 1);
  layer_kernel<<<nlb, 256, 0, stream>>>(XB0, offs, offe, srclist, eps, Wt, bfb, ogb, 2, OUT, (_Float16*)XB1, 0);
}